// Round 11
// baseline (290.115 us; speedup 1.0000x reference)
//
#include <hip/hip_runtime.h>

#define NB 4
#define NC 256
#define NHW 4096
#define NW 64
#define NTOPK 100
#define FMARGIN 4.1f

typedef short s16x8 __attribute__((ext_vector_type(8)));
typedef float f32x4 __attribute__((ext_vector_type(4)));

__device__ __forceinline__ unsigned int tokey(float f) {
    unsigned int u = __float_as_uint(f);
    return (u & 0x80000000u) ? ~u : (u | 0x80000000u);
}
__device__ __forceinline__ float k16tof(unsigned int k) {
    unsigned int k32 = k << 16;
    return __uint_as_float((k32 & 0x80000000u) ? (k32 ^ 0x80000000u) : ~k32);
}
__device__ __forceinline__ unsigned short f2b(float f) {
    unsigned int u = __float_as_uint(f);
    return (unsigned short)((u + 0x7FFFu + ((u >> 16) & 1u)) >> 16);
}

// ---- positive-pair (anchor) selection from the TPS grid ----
__global__ void k_anchor(const float* __restrict__ G, int* __restrict__ ac_flat,
                         int* __restrict__ pvalid) {
    int t = blockIdx.x * 256 + threadIdx.x;
    int b = t >> 12, p = t & (NHW - 1);
    float gxv = G[((size_t)b * NHW + p) * 2 + 0] * 64.0f;
    float gyv = G[((size_t)b * NHW + p) * 2 + 1] * 64.0f;
    float x0 = floorf(gxv), y0 = floorf(gyv);
    float cx[4] = {x0, x0 + 1.f, x0 + 1.f, x0};
    float cy[4] = {y0, y0, y0 + 1.f, y0 + 1.f};
    float d[4]; bool v[4]; float maxd = -INFINITY; bool any = false;
    #pragma unroll
    for (int i = 0; i < 4; ++i) {
        float dx = gxv - cx[i], dy = gyv - cy[i];
        d[i] = sqrtf(dx * dx + dy * dy);
        v[i] = (cx[i] >= 0.f) && (cy[i] >= 0.f) && (cx[i] <= 63.f) && (cy[i] <= 63.f);
        any = any || v[i];
        maxd = fmaxf(maxd, d[i]);
    }
    int sel = 0; float best = -INFINITY;
    #pragma unroll
    for (int i = 0; i < 4; ++i) {
        float prob = v[i] ? ((maxd + 0.3f) - d[i]) : -INFINITY;
        if (prob > best) { best = prob; sel = i; }
    }
    int acx = (int)cx[sel], acy = (int)cy[sel];
    int af = acy * NW + acx;
    af = af < 0 ? 0 : (af > NHW - 1 ? NHW - 1 : af);
    ac_flat[t] = af;
    pvalid[t] = any ? 1 : 0;
}

// ---- fused norm + transpose: sk -> skT[b][q][c] bf16 ----
__global__ void k_packA(const float* __restrict__ sk, unsigned short* __restrict__ skT) {
    __shared__ float tile[64][NC + 1];
    __shared__ float psum[4][64];
    __shared__ float invs[64];
    const int blk = blockIdx.x;
    const int b = blk >> 6;
    const int q0 = (blk & 63) << 6;
    const int t = threadIdx.x;
    const int qloc = t & 63;
    const int c0 = t >> 6;
    const float* base = sk + (size_t)b * NC * NHW + q0 + qloc;
    #pragma unroll 8
    for (int cc = 0; cc < NC; cc += 4) {
        int c = cc + c0;
        tile[qloc][c] = base[(size_t)c * NHW];
    }
    __syncthreads();
    {
        float s = 0.f;
        #pragma unroll 8
        for (int j = 0; j < 64; ++j) { float v = tile[qloc][c0 * 64 + j]; s = fmaf(v, v, s); }
        psum[c0][qloc] = s;
    }
    __syncthreads();
    if (t < 64)
        invs[t] = 1.f / fmaxf(sqrtf(psum[0][t] + psum[1][t] + psum[2][t] + psum[3][t]), 1e-8f);
    __syncthreads();
    const int row = t >> 2, seg = (t & 3) * 64;
    const float iv = invs[row];
    unsigned short* out = skT + ((size_t)b * NHW + q0 + row) * NC + seg;
    #pragma unroll
    for (int j0 = 0; j0 < 64; j0 += 8) {
        unsigned short o[8];
        #pragma unroll
        for (int jj = 0; jj < 8; ++jj) o[jj] = f2b(tile[row][seg + j0 + jj] * iv);
        *(s16x8*)(out + j0) = *(s16x8*)o;
    }
}

// ---- fused norm + pack: rf -> MFMA B layout refP[b][qt][kt][lane][8] bf16 ----
__global__ void k_packB(const float* __restrict__ rf, unsigned short* __restrict__ refP) {
    __shared__ float tile[64][NC + 1];
    __shared__ float psum[4][64];
    __shared__ float invs[64];
    const int blk = blockIdx.x;
    const int b = blk >> 6;
    const int q0 = (blk & 63) << 6;
    const int t = threadIdx.x;
    const int qloc = t & 63;
    const int c0 = t >> 6;
    const float* base = rf + (size_t)b * NC * NHW + q0 + qloc;
    #pragma unroll 8
    for (int cc = 0; cc < NC; cc += 4) {
        int c = cc + c0;
        tile[qloc][c] = base[(size_t)c * NHW];
    }
    __syncthreads();
    {
        float s = 0.f;
        #pragma unroll 8
        for (int j = 0; j < 64; ++j) { float v = tile[qloc][c0 * 64 + j]; s = fmaf(v, v, s); }
        psum[c0][qloc] = s;
    }
    __syncthreads();
    if (t < 64)
        invs[t] = 1.f / fmaxf(sqrtf(psum[0][t] + psum[1][t] + psum[2][t] + psum[3][t]), 1e-8f);
    __syncthreads();
    #pragma unroll
    for (int it = 0; it < 8; ++it) {
        int slot = it * 256 + t;
        int qt = slot >> 9;
        int kt = (slot >> 6) & 7;
        int lane = slot & 63;
        int g = lane >> 4, qll = lane & 15;
        int ql2 = (qt << 4) + qll;
        int c = kt * 32 + g * 8;
        const float iv = invs[ql2];
        unsigned short o[8];
        #pragma unroll
        for (int j = 0; j < 8; ++j) o[j] = f2b(tile[ql2][c + j] * iv);
        size_t oidx = (((size_t)(b * 256 + (q0 >> 4) + qt) * 8 + kt) * 64 + lane) * 8;
        *(s16x8*)(refP + oidx) = *(s16x8*)o;
    }
}

// ---- survivor evaluation: spatial filter + loss accumulate ----
__device__ __forceinline__ void eval_cand(unsigned int pkv, int pg, const float* G, int b,
                                          float px, float py, float base_add,
                                          float& fl, int& ccnt) {
    const int q = (int)(pkv & 4095u);
    bool keep = (q != pg);
    if (keep) {
        float2 g2 = *(const float2*)&G[((size_t)b * NHW + q) * 2];
        float dx = fabsf(g2.x * 4096.f - px), dy = fabsf(g2.y * 4096.f - py);
        keep = !((dx < 1.2f) && (dy < 1.2f));
    }
    if (keep) { fl += base_add + k16tof(pkv >> 12); ccnt++; }
}

// ---- fused MFMA cos + two-half exact top-100 (packed keys) + filtered mean ----
// Columns processed in 2 halves of 2048 so key2 is 64 KB -> ~78 KB LDS total
// -> 2 blocks/CU (8 waves/SIMD): phase B of one block overlaps selection of
// the other. Packed value (key16<<12|col) is unique per column -> the 100th
// smallest packed IS the exact lax.top_k boundary (no tie machinery).
__global__ __launch_bounds__(1024) void k_main(
    const unsigned short* __restrict__ refP, const unsigned short* __restrict__ skT,
    const float* __restrict__ G,
    const int* __restrict__ ac_flat, const int* __restrict__ pvalid,
    float* __restrict__ row_val, int* __restrict__ row_valid)
{
    __shared__ unsigned int key2[8][2048];                    // 64 KB (one half)
    __shared__ __align__(16) unsigned short ancsA[8][64][8];  // 8 KB
    __shared__ unsigned int candL[16][NTOPK];                 // 6.25 KB
    __shared__ float cpp[16];

    const int tid = threadIdx.x;
    const int lane = tid & 63;
    const int w = tid >> 6;      // wave 0..15; owns row w
    const int g = lane >> 4;
    const int ql = lane & 15;
    const int lblk = (blockIdx.x & 7) * 128 + (blockIdx.x >> 3);  // XCD swizzle
    const int b = lblk >> 8;
    const int p0 = (lblk & 255) << 4;

    // ---- phase A: anchors ----
    {
        const int a = ac_flat[b * NHW + p0 + w];
        const unsigned short* src = skT + ((size_t)b * NHW + a) * NC;
        uint2 v = *(const uint2*)(src + lane * 4);
        const int c = lane * 4;
        const int kk = c >> 5, gg = (c >> 3) & 3, j = c & 7;
        *(uint2*)&ancsA[kk][gg * 16 + w][j] = v;
    }
    __syncthreads();

    const int dhalf = p0 >> 11;            // which col-half holds the diagonal
    const int wstar = (p0 & 2047) >> 7;
    const int tstar = (p0 >> 4) & 7;
    const int rp = w >> 1;
    const int hi = (w & 1) << 4;           // row parity -> u16 half shift

    // =================== HALF 0: cols 0..2047 ===================
    {
        s16x8 af0 = *(const s16x8*)&ancsA[0][lane][0];
        s16x8 af1 = *(const s16x8*)&ancsA[1][lane][0];
        s16x8 af2 = *(const s16x8*)&ancsA[2][lane][0];
        s16x8 af3 = *(const s16x8*)&ancsA[3][lane][0];
        s16x8 af4 = *(const s16x8*)&ancsA[4][lane][0];
        s16x8 af5 = *(const s16x8*)&ancsA[5][lane][0];
        s16x8 af6 = *(const s16x8*)&ancsA[6][lane][0];
        s16x8 af7 = *(const s16x8*)&ancsA[7][lane][0];
        #pragma unroll 2
        for (int t = 0; t < 8; ++t) {
            f32x4 a4 = (f32x4){0.f, 0.f, 0.f, 0.f};
            const unsigned short* bpt =
                refP + (((size_t)(b * 256 + 0 * 128 + w * 8 + t) * 8) * 64 + lane) * 8;
            a4 = __builtin_amdgcn_mfma_f32_16x16x32_bf16(af0, *(const s16x8*)(bpt + 0 * 512), a4, 0, 0, 0);
            a4 = __builtin_amdgcn_mfma_f32_16x16x32_bf16(af1, *(const s16x8*)(bpt + 1 * 512), a4, 0, 0, 0);
            a4 = __builtin_amdgcn_mfma_f32_16x16x32_bf16(af2, *(const s16x8*)(bpt + 2 * 512), a4, 0, 0, 0);
            a4 = __builtin_amdgcn_mfma_f32_16x16x32_bf16(af3, *(const s16x8*)(bpt + 3 * 512), a4, 0, 0, 0);
            a4 = __builtin_amdgcn_mfma_f32_16x16x32_bf16(af4, *(const s16x8*)(bpt + 4 * 512), a4, 0, 0, 0);
            a4 = __builtin_amdgcn_mfma_f32_16x16x32_bf16(af5, *(const s16x8*)(bpt + 5 * 512), a4, 0, 0, 0);
            a4 = __builtin_amdgcn_mfma_f32_16x16x32_bf16(af6, *(const s16x8*)(bpt + 6 * 512), a4, 0, 0, 0);
            a4 = __builtin_amdgcn_mfma_f32_16x16x32_bf16(af7, *(const s16x8*)(bpt + 7 * 512), a4, 0, 0, 0);
            if (dhalf == 0 && w == wstar && t == tstar) {
                #pragma unroll
                for (int i = 0; i < 4; ++i)
                    if (ql == g * 4 + i) cpp[g * 4 + i] = a4[i];
            }
            unsigned int k01 = (tokey(a4[0]) >> 16) | ((tokey(a4[1]) >> 16) << 16);
            unsigned int k23 = (tokey(a4[2]) >> 16) | ((tokey(a4[3]) >> 16) << 16);
            const int l_r = (w << 2) + (t >> 1);
            const int j32 = ((t & 1) << 4) + ql;
            const int sx = (j32 >> 2) ^ (l_r & 7);
            const int e = j32 & 3;
            key2[2 * g + 0][(l_r << 5) + ((sx ^ (2 * g + 0)) << 2) + e] = k01;
            key2[2 * g + 1][(l_r << 5) + ((sx ^ (2 * g + 1)) << 2) + e] = k23;
        }
    }
    __syncthreads();

    // ---- sel1: exact top-100 of half 0 into candL[w] ----
    {
        unsigned int pk[32];
        #pragma unroll
        for (int sl = 0; sl < 8; ++sl) {
            const int m = (sl ^ (lane & 7)) ^ rp;
            const uint4 v = *(const uint4*)&key2[rp][(lane << 5) + (m << 2)];
            const unsigned int cb = (unsigned)((lane << 5) + (sl << 2));
            pk[4 * sl + 0] = (((v.x >> hi) & 0xFFFFu) << 12) | (cb + 0);
            pk[4 * sl + 1] = (((v.y >> hi) & 0xFFFFu) << 12) | (cb + 1);
            pk[4 * sl + 2] = (((v.z >> hi) & 0xFFFFu) << 12) | (cb + 2);
            pk[4 * sl + 3] = (((v.w >> hi) & 0xFFFFu) << 12) | (cb + 3);
        }
        unsigned int Ks = 0x4000u << 12;
        #pragma unroll 1
        for (int bit = 26; bit >= 0; --bit) {
            const unsigned int T = Ks | (1u << bit);
            int c = 0;
            #pragma unroll
            for (int j = 0; j < 32; ++j)
                c += __popcll(__ballot(pk[j] < T));
            if (c < NTOPK) Ks = T;
        }
        int cl = 0;
        #pragma unroll
        for (int j = 0; j < 32; ++j) cl += (pk[j] <= Ks) ? 1 : 0;
        int ep = cl;
        #pragma unroll
        for (int d = 1; d < 64; d <<= 1) {
            int t2 = __shfl_up(ep, d, 64);
            if (lane >= d) ep += t2;
        }
        ep -= cl;
        #pragma unroll
        for (int j = 0; j < 32; ++j)
            if (pk[j] <= Ks) candL[w][ep++] = pk[j];
    }
    __syncthreads();

    // =================== HALF 1: cols 2048..4095 ===================
    {
        s16x8 af0 = *(const s16x8*)&ancsA[0][lane][0];
        s16x8 af1 = *(const s16x8*)&ancsA[1][lane][0];
        s16x8 af2 = *(const s16x8*)&ancsA[2][lane][0];
        s16x8 af3 = *(const s16x8*)&ancsA[3][lane][0];
        s16x8 af4 = *(const s16x8*)&ancsA[4][lane][0];
        s16x8 af5 = *(const s16x8*)&ancsA[5][lane][0];
        s16x8 af6 = *(const s16x8*)&ancsA[6][lane][0];
        s16x8 af7 = *(const s16x8*)&ancsA[7][lane][0];
        #pragma unroll 2
        for (int t = 0; t < 8; ++t) {
            f32x4 a4 = (f32x4){0.f, 0.f, 0.f, 0.f};
            const unsigned short* bpt =
                refP + (((size_t)(b * 256 + 128 + w * 8 + t) * 8) * 64 + lane) * 8;
            a4 = __builtin_amdgcn_mfma_f32_16x16x32_bf16(af0, *(const s16x8*)(bpt + 0 * 512), a4, 0, 0, 0);
            a4 = __builtin_amdgcn_mfma_f32_16x16x32_bf16(af1, *(const s16x8*)(bpt + 1 * 512), a4, 0, 0, 0);
            a4 = __builtin_amdgcn_mfma_f32_16x16x32_bf16(af2, *(const s16x8*)(bpt + 2 * 512), a4, 0, 0, 0);
            a4 = __builtin_amdgcn_mfma_f32_16x16x32_bf16(af3, *(const s16x8*)(bpt + 3 * 512), a4, 0, 0, 0);
            a4 = __builtin_amdgcn_mfma_f32_16x16x32_bf16(af4, *(const s16x8*)(bpt + 4 * 512), a4, 0, 0, 0);
            a4 = __builtin_amdgcn_mfma_f32_16x16x32_bf16(af5, *(const s16x8*)(bpt + 5 * 512), a4, 0, 0, 0);
            a4 = __builtin_amdgcn_mfma_f32_16x16x32_bf16(af6, *(const s16x8*)(bpt + 6 * 512), a4, 0, 0, 0);
            a4 = __builtin_amdgcn_mfma_f32_16x16x32_bf16(af7, *(const s16x8*)(bpt + 7 * 512), a4, 0, 0, 0);
            if (dhalf == 1 && w == wstar && t == tstar) {
                #pragma unroll
                for (int i = 0; i < 4; ++i)
                    if (ql == g * 4 + i) cpp[g * 4 + i] = a4[i];
            }
            unsigned int k01 = (tokey(a4[0]) >> 16) | ((tokey(a4[1]) >> 16) << 16);
            unsigned int k23 = (tokey(a4[2]) >> 16) | ((tokey(a4[3]) >> 16) << 16);
            const int l_r = (w << 2) + (t >> 1);
            const int j32 = ((t & 1) << 4) + ql;
            const int sx = (j32 >> 2) ^ (l_r & 7);
            const int e = j32 & 3;
            key2[2 * g + 0][(l_r << 5) + ((sx ^ (2 * g + 0)) << 2) + e] = k01;
            key2[2 * g + 1][(l_r << 5) + ((sx ^ (2 * g + 1)) << 2) + e] = k23;
        }
    }
    __syncthreads();

    // ---- sel2: merge half-1 keys with candL; filter; sum ----
    {
        unsigned int pk[32];
        #pragma unroll
        for (int sl = 0; sl < 8; ++sl) {
            const int m = (sl ^ (lane & 7)) ^ rp;
            const uint4 v = *(const uint4*)&key2[rp][(lane << 5) + (m << 2)];
            const unsigned int cb = (unsigned)(2048 + (lane << 5) + (sl << 2));
            pk[4 * sl + 0] = (((v.x >> hi) & 0xFFFFu) << 12) | (cb + 0);
            pk[4 * sl + 1] = (((v.y >> hi) & 0xFFFFu) << 12) | (cb + 1);
            pk[4 * sl + 2] = (((v.z >> hi) & 0xFFFFu) << 12) | (cb + 2);
            pk[4 * sl + 3] = (((v.w >> hi) & 0xFFFFu) << 12) | (cb + 3);
        }
        const unsigned int c0 = candL[w][lane];
        const unsigned int c1 = (lane < NTOPK - 64) ? candL[w][64 + lane] : 0xFFFFFFFFu;

        unsigned int Ks = 0x4000u << 12;
        #pragma unroll 1
        for (int bit = 26; bit >= 0; --bit) {
            const unsigned int T = Ks | (1u << bit);
            int c = 0;
            #pragma unroll
            for (int j = 0; j < 32; ++j)
                c += __popcll(__ballot(pk[j] < T));
            c += __popcll(__ballot(c0 < T));
            c += __popcll(__ballot(c1 < T));
            if (c < NTOPK) Ks = T;
        }

        const float dpos = 1.0f - cpp[w];
        const int pg = p0 + w;
        const float2 gp = *(const float2*)&G[((size_t)b * NHW + pg) * 2];
        const float px = gp.x * 4096.f, py = gp.y * 4096.f;
        const float base_add = dpos + (FMARGIN - 1.0f);

        float fl = 0.f; int ccnt = 0;
        #pragma unroll
        for (int j = 0; j < 32; ++j)
            if (pk[j] <= Ks) eval_cand(pk[j], pg, G, b, px, py, base_add, fl, ccnt);
        if (c0 <= Ks) eval_cand(c0, pg, G, b, px, py, base_add, fl, ccnt);
        if (c1 <= Ks) eval_cand(c1, pg, G, b, px, py, base_add, fl, ccnt);

        #pragma unroll
        for (int d = 1; d < 64; d <<= 1) {
            fl += __shfl_xor(fl, d, 64);
            ccnt += __shfl_xor(ccnt, d, 64);
        }
        if (lane == 0) {
            const int pv = (pvalid[b * NHW + pg] != 0) && (ccnt > 0);
            row_val[b * NHW + pg] = pv ? (fl / (float)ccnt) : 0.f;
            row_valid[b * NHW + pg] = pv;
        }
    }
}

// ---- final deterministic reduction ----
__global__ void k_reduce(const float* __restrict__ row_val, const int* __restrict__ row_valid,
                         float* __restrict__ out) {
    __shared__ float ss[256];
    __shared__ int sc[256];
    float s = 0.f; int n = 0;
    for (int i = threadIdx.x; i < NB * NHW; i += 256) { s += row_val[i]; n += row_valid[i]; }
    ss[threadIdx.x] = s; sc[threadIdx.x] = n;
    __syncthreads();
    for (int d = 128; d > 0; d >>= 1) {
        if (threadIdx.x < d) { ss[threadIdx.x] += ss[threadIdx.x + d]; sc[threadIdx.x] += sc[threadIdx.x + d]; }
        __syncthreads();
    }
    if (threadIdx.x == 0) out[0] = ss[0] / (1e-6f + (float)sc[0]);
}

extern "C" void kernel_launch(void* const* d_in, const int* in_sizes, int n_in,
                              void* d_out, int out_size, void* d_ws, size_t ws_size,
                              hipStream_t stream) {
    const float* sk = (const float*)d_in[0];
    const float* rf = (const float*)d_in[1];
    const float* G  = (const float*)d_in[2];
    char* ws = (char*)d_ws;
    const size_t PANEL = (size_t)NB * NC * NHW * 2;   // 8 MB
    int*   ac  = (int*)  (ws + 0 * 65536);
    int*   pv  = (int*)  (ws + 1 * 65536);
    float* rv_ = (float*)(ws + 2 * 65536);
    int*   rvd = (int*)  (ws + 3 * 65536);
    unsigned short* rf16 = (unsigned short*)(ws + 4 * 65536);
    unsigned short* skT  = (unsigned short*)(ws + 4 * 65536 + PANEL);

    hipLaunchKernelGGL(k_anchor, dim3(64), dim3(256), 0, stream, G, ac, pv);
    hipLaunchKernelGGL(k_packB, dim3(256), dim3(256), 0, stream, rf, rf16);
    hipLaunchKernelGGL(k_packA, dim3(256), dim3(256), 0, stream, sk, skT);
    hipLaunchKernelGGL(k_main, dim3(1024), dim3(1024), 0, stream,
                       rf16, skT, G, ac, pv, rv_, rvd);
    hipLaunchKernelGGL(k_reduce, dim3(1), dim3(256), 0, stream, rv_, rvd, (float*)d_out);
}

// Round 12
// 251.866 us; speedup vs baseline: 1.1519x; 1.1519x over previous
//
#include <hip/hip_runtime.h>

#define NB 4
#define NC 256
#define NHW 4096
#define NW 64
#define NTOPK 100
#define FMARGIN 4.1f

typedef float f32x4 __attribute__((ext_vector_type(4)));

__device__ __forceinline__ unsigned int tokey(float f) {
    unsigned int u = __float_as_uint(f);
    return (u & 0x80000000u) ? ~u : (u | 0x80000000u);
}
__device__ __forceinline__ float k16tof(unsigned int k) {
    unsigned int k32 = k << 16;
    return __uint_as_float((k32 & 0x80000000u) ? (k32 ^ 0x80000000u) : ~k32);
}

// ---- positive-pair (anchor) selection from the TPS grid ----
__global__ void k_anchor(const float* __restrict__ G, int* __restrict__ ac_flat,
                         int* __restrict__ pvalid) {
    int t = blockIdx.x * 256 + threadIdx.x;
    int b = t >> 12, p = t & (NHW - 1);
    float gxv = G[((size_t)b * NHW + p) * 2 + 0] * 64.0f;
    float gyv = G[((size_t)b * NHW + p) * 2 + 1] * 64.0f;
    float x0 = floorf(gxv), y0 = floorf(gyv);
    float cx[4] = {x0, x0 + 1.f, x0 + 1.f, x0};
    float cy[4] = {y0, y0, y0 + 1.f, y0 + 1.f};
    float d[4]; bool v[4]; float maxd = -INFINITY; bool any = false;
    #pragma unroll
    for (int i = 0; i < 4; ++i) {
        float dx = gxv - cx[i], dy = gyv - cy[i];
        d[i] = sqrtf(dx * dx + dy * dy);
        v[i] = (cx[i] >= 0.f) && (cy[i] >= 0.f) && (cx[i] <= 63.f) && (cy[i] <= 63.f);
        any = any || v[i];
        maxd = fmaxf(maxd, d[i]);
    }
    int sel = 0; float best = -INFINITY;
    #pragma unroll
    for (int i = 0; i < 4; ++i) {
        float prob = v[i] ? ((maxd + 0.3f) - d[i]) : -INFINITY;
        if (prob > best) { best = prob; sel = i; }
    }
    int acx = (int)cx[sel], acy = (int)cy[sel];
    int af = acy * NW + acx;
    af = af < 0 ? 0 : (af > NHW - 1 ? NHW - 1 : af);
    ac_flat[t] = af;
    pvalid[t] = any ? 1 : 0;
}

// ---- fused norm + transpose: sk -> skT[b][q][c] fp8 e4m3 ----
__global__ void k_packA(const float* __restrict__ sk, unsigned char* __restrict__ skT) {
    __shared__ float tile[64][NC + 1];
    __shared__ float psum[4][64];
    __shared__ float invs[64];
    const int blk = blockIdx.x;
    const int b = blk >> 6;
    const int q0 = (blk & 63) << 6;
    const int t = threadIdx.x;
    const int qloc = t & 63;
    const int c0 = t >> 6;
    const float* base = sk + (size_t)b * NC * NHW + q0 + qloc;
    #pragma unroll 8
    for (int cc = 0; cc < NC; cc += 4) {
        int c = cc + c0;
        tile[qloc][c] = base[(size_t)c * NHW];
    }
    __syncthreads();
    {
        float s = 0.f;
        #pragma unroll 8
        for (int j = 0; j < 64; ++j) { float v = tile[qloc][c0 * 64 + j]; s = fmaf(v, v, s); }
        psum[c0][qloc] = s;
    }
    __syncthreads();
    if (t < 64)
        invs[t] = 1.f / fmaxf(sqrtf(psum[0][t] + psum[1][t] + psum[2][t] + psum[3][t]), 1e-8f);
    __syncthreads();
    const int row = t >> 2, seg = (t & 3) * 64;
    const float iv = invs[row];
    unsigned char* out = skT + ((size_t)b * NHW + q0 + row) * NC + seg;
    #pragma unroll
    for (int j0 = 0; j0 < 64; j0 += 8) {
        unsigned int r0 = 0u, r1 = 0u;
        r0 = __builtin_amdgcn_cvt_pk_fp8_f32(tile[row][seg + j0 + 0] * iv, tile[row][seg + j0 + 1] * iv, r0, false);
        r0 = __builtin_amdgcn_cvt_pk_fp8_f32(tile[row][seg + j0 + 2] * iv, tile[row][seg + j0 + 3] * iv, r0, true);
        r1 = __builtin_amdgcn_cvt_pk_fp8_f32(tile[row][seg + j0 + 4] * iv, tile[row][seg + j0 + 5] * iv, r1, false);
        r1 = __builtin_amdgcn_cvt_pk_fp8_f32(tile[row][seg + j0 + 6] * iv, tile[row][seg + j0 + 7] * iv, r1, true);
        *(uint2*)(out + j0) = make_uint2(r0, r1);
    }
}

// ---- fused norm + pack: rf -> MFMA B layout refP[b][qt][kt][lane][8] fp8 ----
__global__ void k_packB(const float* __restrict__ rf, unsigned char* __restrict__ refP) {
    __shared__ float tile[64][NC + 1];
    __shared__ float psum[4][64];
    __shared__ float invs[64];
    const int blk = blockIdx.x;
    const int b = blk >> 6;
    const int q0 = (blk & 63) << 6;
    const int t = threadIdx.x;
    const int qloc = t & 63;
    const int c0 = t >> 6;
    const float* base = rf + (size_t)b * NC * NHW + q0 + qloc;
    #pragma unroll 8
    for (int cc = 0; cc < NC; cc += 4) {
        int c = cc + c0;
        tile[qloc][c] = base[(size_t)c * NHW];
    }
    __syncthreads();
    {
        float s = 0.f;
        #pragma unroll 8
        for (int j = 0; j < 64; ++j) { float v = tile[qloc][c0 * 64 + j]; s = fmaf(v, v, s); }
        psum[c0][qloc] = s;
    }
    __syncthreads();
    if (t < 64)
        invs[t] = 1.f / fmaxf(sqrtf(psum[0][t] + psum[1][t] + psum[2][t] + psum[3][t]), 1e-8f);
    __syncthreads();
    #pragma unroll
    for (int it = 0; it < 8; ++it) {
        int slot = it * 256 + t;
        int qt = slot >> 9;
        int kt = (slot >> 6) & 7;
        int lane = slot & 63;
        int g = lane >> 4, qll = lane & 15;
        int ql2 = (qt << 4) + qll;
        int c = kt * 32 + g * 8;
        const float iv = invs[ql2];
        unsigned int r0 = 0u, r1 = 0u;
        r0 = __builtin_amdgcn_cvt_pk_fp8_f32(tile[ql2][c + 0] * iv, tile[ql2][c + 1] * iv, r0, false);
        r0 = __builtin_amdgcn_cvt_pk_fp8_f32(tile[ql2][c + 2] * iv, tile[ql2][c + 3] * iv, r0, true);
        r1 = __builtin_amdgcn_cvt_pk_fp8_f32(tile[ql2][c + 4] * iv, tile[ql2][c + 5] * iv, r1, false);
        r1 = __builtin_amdgcn_cvt_pk_fp8_f32(tile[ql2][c + 6] * iv, tile[ql2][c + 7] * iv, r1, true);
        size_t oidx = (((size_t)(b * 256 + (q0 >> 4) + qt) * 8 + kt) * 64 + lane) * 8;
        *(uint2*)(refP + oidx) = make_uint2(r0, r1);
    }
}

// ---- fused FP8-MFMA cos + wave-local selection (round-10 structure) ----
// FP8 e4m3 operands: same fragment geometry as bf16 16x16x32 but 8B/lane ->
// phase-B loads halve (64 dwordx2 vs 128 dwordx4), L2 panel 2MB -> 1MB.
// kappa-symmetry: A and B packed with the SAME channel<->(g,j) map, so the
// HW k-order cancels; C layout is shape-determined (dtype-independent).
__global__ __attribute__((amdgpu_flat_work_group_size(1024, 1024), amdgpu_waves_per_eu(4, 4)))
void k_main(const unsigned char* __restrict__ refP, const unsigned char* __restrict__ skT,
            const float* __restrict__ G,
            const int* __restrict__ ac_flat, const int* __restrict__ pvalid,
            float* __restrict__ row_val, int* __restrict__ row_valid)
{
    __shared__ unsigned int key2[8][NHW];                    // 128 KB
    __shared__ __align__(16) unsigned char ancsA[8][64][8];  // 4 KB
    __shared__ float cpp[16];

    const int tid = threadIdx.x;
    const int lane = tid & 63;
    const int w = tid >> 6;
    const int g = lane >> 4;
    const int ql = lane & 15;
    const int lblk = (blockIdx.x & 7) * 128 + (blockIdx.x >> 3);
    const int b = lblk >> 8;
    const int p0 = (lblk & 255) << 4;

    // ---- phase A: anchors (fp8, 4 ch per lane-load) ----
    {
        const int a = ac_flat[b * NHW + p0 + w];
        const unsigned char* src = skT + ((size_t)b * NHW + a) * NC;
        unsigned int v = *(const unsigned int*)(src + lane * 4);
        const int c = lane * 4;
        const int kk = c >> 5, gg = (c >> 3) & 3, j = c & 7;
        *(unsigned int*)&ancsA[kk][gg * 16 + w][j] = v;
    }
    __syncthreads();

    // ---- phase B: FP8 MFMA, keys to swizzled key2 ----
    const int wstar = p0 >> 8;
    const int tstar = (p0 >> 4) & 15;
    long long af0 = *(const long long*)&ancsA[0][lane][0];
    long long af1 = *(const long long*)&ancsA[1][lane][0];
    long long af2 = *(const long long*)&ancsA[2][lane][0];
    long long af3 = *(const long long*)&ancsA[3][lane][0];
    long long af4 = *(const long long*)&ancsA[4][lane][0];
    long long af5 = *(const long long*)&ancsA[5][lane][0];
    long long af6 = *(const long long*)&ancsA[6][lane][0];
    long long af7 = *(const long long*)&ancsA[7][lane][0];

    #pragma unroll 4
    for (int t = 0; t < 16; ++t) {
        f32x4 a4 = (f32x4){0.f, 0.f, 0.f, 0.f};
        const unsigned char* bpt =
            refP + (((size_t)(b * 256 + w * 16 + t) * 8) * 64 + lane) * 8;
        a4 = __builtin_amdgcn_mfma_f32_16x16x32_fp8_fp8(af0, *(const long long*)(bpt + 0 * 512), a4, 0, 0, 0);
        a4 = __builtin_amdgcn_mfma_f32_16x16x32_fp8_fp8(af1, *(const long long*)(bpt + 1 * 512), a4, 0, 0, 0);
        a4 = __builtin_amdgcn_mfma_f32_16x16x32_fp8_fp8(af2, *(const long long*)(bpt + 2 * 512), a4, 0, 0, 0);
        a4 = __builtin_amdgcn_mfma_f32_16x16x32_fp8_fp8(af3, *(const long long*)(bpt + 3 * 512), a4, 0, 0, 0);
        a4 = __builtin_amdgcn_mfma_f32_16x16x32_fp8_fp8(af4, *(const long long*)(bpt + 4 * 512), a4, 0, 0, 0);
        a4 = __builtin_amdgcn_mfma_f32_16x16x32_fp8_fp8(af5, *(const long long*)(bpt + 5 * 512), a4, 0, 0, 0);
        a4 = __builtin_amdgcn_mfma_f32_16x16x32_fp8_fp8(af6, *(const long long*)(bpt + 6 * 512), a4, 0, 0, 0);
        a4 = __builtin_amdgcn_mfma_f32_16x16x32_fp8_fp8(af7, *(const long long*)(bpt + 7 * 512), a4, 0, 0, 0);
        if (w == wstar && t == tstar) {
            #pragma unroll
            for (int i = 0; i < 4; ++i)
                if (ql == g * 4 + i) cpp[g * 4 + i] = a4[i];
        }
        unsigned int k01 = (tokey(a4[0]) >> 16) | ((tokey(a4[1]) >> 16) << 16);
        unsigned int k23 = (tokey(a4[2]) >> 16) | ((tokey(a4[3]) >> 16) << 16);
        const int l_r = (w << 2) + (t >> 2);
        const int ach = ((t & 3) << 2) + (ql >> 2);
        const int pidx = (l_r << 6) + ((ach ^ (l_r & 15)) << 2) + (ql & 3);
        key2[(g << 1) + 0][pidx] = k01;
        key2[(g << 1) + 1][pidx] = k23;
    }
    __syncthreads();

    // ---- wave-local selection: wave w owns row w ----
    const int rp = w >> 1;
    const int half = w & 1;
    unsigned int ku[64];   // ku[4*ach+m] = key for col lane*64 + 8*ach + 2*m + half
    #pragma unroll
    for (int ach = 0; ach < 16; ++ach) {
        const uint4 v = *(const uint4*)&key2[rp][(lane << 6) + ((ach ^ (lane & 15)) << 2)];
        ku[4 * ach + 0] = half ? (v.x >> 16) : (v.x & 0xFFFFu);
        ku[4 * ach + 1] = half ? (v.y >> 16) : (v.y & 0xFFFFu);
        ku[4 * ach + 2] = half ? (v.z >> 16) : (v.z & 0xFFFFu);
        ku[4 * ach + 3] = half ? (v.w >> 16) : (v.w & 0xFFFFu);
    }

    // exact 100th-smallest key: ballot binary search over bits 14..0
    unsigned int Ks = 0x4000u;
    #pragma unroll 1
    for (int bit = 14; bit >= 0; --bit) {
        const unsigned int T = Ks | (1u << bit);
        int c = 0;
        #pragma unroll
        for (int j = 0; j < 64; ++j)
            c += __popcll(__ballot(ku[j] < T));
        if (c < NTOPK) Ks = T;
    }
    int below = 0;
    #pragma unroll
    for (int j = 0; j < 64; ++j)
        below += __popcll(__ballot(ku[j] < Ks));
    const int tk = NTOPK - below;

    // ---- scan: strictly-below kept (filtered); ties by ascending col ----
    const float dpos = 1.0f - cpp[w];
    const int pg = p0 + w;
    const float2 gp = *(const float2*)&G[((size_t)b * NHW + pg) * 2];
    const float px = gp.x * 4096.f, py = gp.y * 4096.f;
    const float base_add = dpos + (FMARGIN - 1.0f);

    float sumv = 0.f; int cnt = 0;
    unsigned long long tmask = 0ull; int ltc = 0;
    #pragma unroll
    for (int j = 0; j < 64; ++j) {
        const unsigned int k = ku[j];
        if (k < Ks) {
            const int q = (lane << 6) + 8 * (j >> 2) + 2 * (j & 3) + half;
            bool keep = (q != pg);
            if (keep) {
                float2 g2 = *(const float2*)&G[((size_t)b * NHW + q) * 2];
                float dx = fabsf(g2.x * 4096.f - px), dy = fabsf(g2.y * 4096.f - py);
                keep = !((dx < 1.2f) && (dy < 1.2f));
            }
            if (keep) { sumv += k16tof(k); cnt++; }
        } else if (k == Ks) {
            tmask |= (1ull << j);
            ltc++;
        }
    }
    int pfx = ltc;
    #pragma unroll
    for (int d = 1; d < 64; d <<= 1) {
        int t2 = __shfl_up(pfx, d, 64);
        if (lane >= d) pfx += t2;
    }
    pfx -= ltc;
    int ek = 0;
    if (ltc > 0 && pfx < tk) {
        unsigned long long mm = tmask;
        int m = 0;
        while (mm) {
            const int j = __ffsll((unsigned long long)mm) - 1;
            mm &= mm - 1;
            if (pfx + m < tk) {
                const int q = (lane << 6) + 8 * (j >> 2) + 2 * (j & 3) + half;
                bool keep = (q != pg);
                if (keep) {
                    float2 g2 = *(const float2*)&G[((size_t)b * NHW + q) * 2];
                    float dx = fabsf(g2.x * 4096.f - px), dy = fabsf(g2.y * 4096.f - py);
                    keep = !((dx < 1.2f) && (dy < 1.2f));
                }
                if (keep) ek++;
            }
            m++;
        }
    }
    const float vstar = k16tof(Ks);
    float fl = sumv + (float)cnt * base_add + (float)ek * (base_add + vstar);
    int ccnt = cnt + ek;
    #pragma unroll
    for (int d = 1; d < 64; d <<= 1) {
        fl += __shfl_xor(fl, d, 64);
        ccnt += __shfl_xor(ccnt, d, 64);
    }
    if (lane == 0) {
        const int pv = (pvalid[b * NHW + pg] != 0) && (ccnt > 0);
        row_val[b * NHW + pg] = pv ? (fl / (float)ccnt) : 0.f;
        row_valid[b * NHW + pg] = pv;
    }
}

// ---- final deterministic reduction ----
__global__ void k_reduce(const float* __restrict__ row_val, const int* __restrict__ row_valid,
                         float* __restrict__ out) {
    __shared__ float ss[256];
    __shared__ int sc[256];
    float s = 0.f; int n = 0;
    for (int i = threadIdx.x; i < NB * NHW; i += 256) { s += row_val[i]; n += row_valid[i]; }
    ss[threadIdx.x] = s; sc[threadIdx.x] = n;
    __syncthreads();
    for (int d = 128; d > 0; d >>= 1) {
        if (threadIdx.x < d) { ss[threadIdx.x] += ss[threadIdx.x + d]; sc[threadIdx.x] += sc[threadIdx.x + d]; }
        __syncthreads();
    }
    if (threadIdx.x == 0) out[0] = ss[0] / (1e-6f + (float)sc[0]);
}

extern "C" void kernel_launch(void* const* d_in, const int* in_sizes, int n_in,
                              void* d_out, int out_size, void* d_ws, size_t ws_size,
                              hipStream_t stream) {
    const float* sk = (const float*)d_in[0];
    const float* rf = (const float*)d_in[1];
    const float* G  = (const float*)d_in[2];
    char* ws = (char*)d_ws;
    const size_t PANEL8 = (size_t)NB * NC * NHW;      // 4 MB (fp8)
    int*   ac  = (int*)  (ws + 0 * 65536);
    int*   pv  = (int*)  (ws + 1 * 65536);
    float* rv_ = (float*)(ws + 2 * 65536);
    int*   rvd = (int*)  (ws + 3 * 65536);
    unsigned char* rf8 = (unsigned char*)(ws + 4 * 65536);
    unsigned char* sk8 = (unsigned char*)(ws + 4 * 65536 + PANEL8);

    hipLaunchKernelGGL(k_anchor, dim3(64), dim3(256), 0, stream, G, ac, pv);
    hipLaunchKernelGGL(k_packB, dim3(256), dim3(256), 0, stream, rf, rf8);
    hipLaunchKernelGGL(k_packA, dim3(256), dim3(256), 0, stream, sk, sk8);
    hipLaunchKernelGGL(k_main, dim3(1024), dim3(1024), 0, stream,
                       rf8, sk8, G, ac, pv, rv_, rvd);
    hipLaunchKernelGGL(k_reduce, dim3(1), dim3(256), 0, stream, rv_, rvd, (float*)d_out);
}